// Round 1
// baseline (320.186 us; speedup 1.0000x reference)
//
#include <hip/hip_runtime.h>

// entmax-1.5 over rows of an 8192 x 4096 fp32 matrix, boolean mask (int32).
// R9 = R8 structure (one 256-thread block per row, z[16] fp32 per thread,
// ballot-compacted candidates in LDS, barrier-free redundant wave solve)
// with ALL cross-lane reductions moved from __shfl_xor (ds_bpermute chains,
// ~30-120cy DS latency per level, 6 serial levels x 3 sums x 8 iters) onto
// full-rate VALU DPP (row_shr 1/2/4/8 + row_bcast 15/31 + readlane 63).
// This was the stall: rocprof R8 showed VALUBusy 35% / HBM 28% / occ 68%
// (latency-bound, no pipe saturated) with ~1200 of ~1540 VALU insts/wave in
// the solve's shuffle butterflies. DPP reductions issue on the VALU pipe with
// no lgkmcnt waits and return the total as a uniform SGPR (t is wave-uniform,
// so all downstream z[i]-t ops get t as the free scalar operand).
// Also: output is write-once/never-read -> nontemporal stores, so the 128 MiB
// out stream doesn't evict not-yet-read input rows from the 256 MiB L3.

constexpr int NROWS = 8192;
constexpr int NCOL  = 4096;
constexpr int EPT   = 16;   // elements per thread (4096 / 256)
constexpr int NLD   = 4;    // float4/int4 loads per thread
constexpr int CAP   = 128;  // candidate slots per wave region
constexpr int MAXIT = 8;    // solve cap; exact-quadratic typically 2-4 iters

typedef float f32x4 __attribute__((ext_vector_type(4)));

static __device__ __forceinline__ int mbcnt64(unsigned long long m) {
    // popcount of m restricted to lanes below this lane
    return __builtin_amdgcn_mbcnt_hi((unsigned)(m >> 32),
           __builtin_amdgcn_mbcnt_lo((unsigned)m, 0));
}

// ---- DPP wave reductions (gfx9 canonical; all-VALU, no DS pipe) ----------
// update_dpp: lanes masked out by row/bank mask, or with no valid source
// (bound_ctrl=false), receive `oldv`. For sum: oldv=0 is the identity.
// For max: oldv=x makes masked lanes a no-op under fmax.
template <int CTRL, int RMASK, int BMASK, bool BOUND>
static __device__ __forceinline__ float dpp_f32(float oldv, float src) {
    return __int_as_float(__builtin_amdgcn_update_dpp(
        __float_as_int(oldv), __float_as_int(src), CTRL, RMASK, BMASK, BOUND));
}

// Wave-wide sum; result returned uniform (readlane 63 -> SGPR).
static __device__ __forceinline__ float wave_sum(float x) {
    x += dpp_f32<0x111, 0xf, 0xf, true>(0.f, x);   // row_shr:1
    x += dpp_f32<0x112, 0xf, 0xf, true>(0.f, x);   // row_shr:2
    x += dpp_f32<0x114, 0xf, 0xe, true>(0.f, x);   // row_shr:4
    x += dpp_f32<0x118, 0xf, 0xc, true>(0.f, x);   // row_shr:8
    x += dpp_f32<0x142, 0xa, 0xf, true>(0.f, x);   // row_bcast:15 -> rows 1,3
    x += dpp_f32<0x143, 0xc, 0xf, true>(0.f, x);   // row_bcast:31 -> rows 2,3
    return __int_as_float(__builtin_amdgcn_readlane(__float_as_int(x), 63));
}

// Wave-wide max; result returned uniform (readlane 63 -> SGPR).
static __device__ __forceinline__ float wave_max(float x) {
    x = fmaxf(x, dpp_f32<0x111, 0xf, 0xf, false>(x, x));
    x = fmaxf(x, dpp_f32<0x112, 0xf, 0xf, false>(x, x));
    x = fmaxf(x, dpp_f32<0x114, 0xf, 0xf, false>(x, x));
    x = fmaxf(x, dpp_f32<0x118, 0xf, 0xf, false>(x, x));
    x = fmaxf(x, dpp_f32<0x142, 0xa, 0xf, false>(x, x));
    x = fmaxf(x, dpp_f32<0x143, 0xc, 0xf, false>(x, x));
    return __int_as_float(__builtin_amdgcn_readlane(__float_as_int(x), 63));
}

__global__ __launch_bounds__(256, 8)
void entmax15_kernel(const float* __restrict__ scores,
                     const int*   __restrict__ mask,
                     float*       __restrict__ out)
{
    __shared__ float cand[4 * CAP];   // wave w owns [w*CAP, (w+1)*CAP)
    __shared__ float redA[4], redB[4];
    __shared__ int   ovfl;

    const int tid  = threadIdx.x;
    const int lane = tid & 63;
    const int wave = tid >> 6;
    const int row  = blockIdx.x;

    const float* srow = scores + (size_t)row * NCOL;
    const int*   mrow = mask   + (size_t)row * NCOL;
    float*       orow = out    + (size_t)row * NCOL;

    float z[EPT];

    // Coalesced loads: sweep c covers cols [c*1024, c*1024+1024), thread takes
    // 4 consecutive floats at c*1024 + tid*4 (16B aligned).
    #pragma unroll
    for (int c = 0; c < NLD; ++c) {
        const int base = c * 1024 + tid * 4;
        const float4 s4 = *reinterpret_cast<const float4*>(srow + base);
        const int4   m4 = *reinterpret_cast<const int4*>(mrow + base);
        z[c * 4 + 0] = m4.x ? s4.x * 0.5f : -5000.0f;  // where(mask, s/2, -5000)
        z[c * 4 + 1] = m4.y ? s4.y * 0.5f : -5000.0f;
        z[c * 4 + 2] = m4.z ? s4.z * 0.5f : -5000.0f;
        z[c * 4 + 3] = m4.w ? s4.w * 0.5f : -5000.0f;
    }

    // Init (before barrier 1): overflow flag + own region's sentinels.
    // Wave-internal ordering makes the later compaction writes safe.
    if (tid == 0) ovfl = 0;
    cand[wave * CAP + lane]      = -1e30f;
    cand[wave * CAP + lane + 64] = -1e30f;

    // Row max: lane tree, DPP wave max (VALU-only), 4-wave LDS combine.
    float mx = z[0];
    #pragma unroll
    for (int i = 1; i < EPT; ++i) mx = fmaxf(mx, z[i]);
    mx = wave_max(mx);
    if (lane == 0) redA[wave] = mx;
    __syncthreads();                  // barrier 1
    mx = fmaxf(fmaxf(redA[0], redA[1]), fmaxf(redA[2], redA[3]));
    const float thresh = mx - 1.0f;   // tau* >= thresh: z <= thresh are dead

    // Compact candidates into this wave's region: 16 ballot rounds.
    int cnt = 0;
    #pragma unroll
    for (int i = 0; i < EPT; ++i) {
        const bool isc = z[i] > thresh;
        const unsigned long long m = __ballot(isc);
        if (isc) {
            const int pos = cnt + mbcnt64(m);
            if (pos < CAP) cand[wave * CAP + pos] = z[i];
        }
        cnt += (int)__popcll(m);      // wave-uniform
    }
    if (lane == 0 && cnt > CAP) ovfl = 1;
    __syncthreads();                  // barrier 2: compaction visible

    float t = thresh;                 // left bracket: g(thresh) >= 0

    if (ovfl == 0) {
        // Barrier-free solve: each wave redundantly reads ALL 512 slots,
        // 8 per lane at stride 64 (conflict-free), sentinels give d=0.
        float cv[8];
        #pragma unroll
        for (int k = 0; k < 8; ++k) cv[k] = cand[k * 64 + lane];

        // Exact piecewise-quadratic iteration: on the support at t,
        // s0 u^2 - 2 s1 u + (s2-1) = 0; u = (s1 - sqrt(disc))/s0 (smaller
        // root); disc<0 -> vertex jump; overshoot self-corrects (u<0).
        // The 3 wave_sum chains are independent -> the compiler interleaves
        // their DPP steps; total reduce latency ~6 dependent VALU ops.
        #pragma unroll 1
        for (int it = 0; it < MAXIT; ++it) {
            float s0 = 0.f, s1 = 0.f, s2 = 0.f;
            #pragma unroll
            for (int k = 0; k < 8; ++k) {
                const float d = fmaxf(cv[k] - t, 0.f);
                s2 = fmaf(d, d, s2);
                s1 += d;
                s0 += (d > 0.f) ? 1.0f : 0.0f;
            }
            s0 = wave_sum(s0);
            s1 = wave_sum(s1);
            s2 = wave_sum(s2);
            const float s0c  = fmaxf(s0, 1.0f);     // s0>=1 at t<=tau*<mx
            const float disc = fmaf(s1, s1, -s0c * (s2 - 1.0f));
            const float u    = (s1 - sqrtf(fmaxf(disc, 0.f))) / s0c;
            t += u;                                  // wave-uniform (SGPR)
            if (__builtin_fabsf(u) < 5e-7f) break;   // wave-uniform break
        }
        // All 4 waves computed bit-identical t from identical data.
    } else {
        // Fallback (pathological rows): R6-style Newton, block reduction.
        #pragma unroll 1
        for (int it = 0; it < 10; ++it) {
            float s2 = 0.f, s1 = 0.f;
            #pragma unroll
            for (int i = 0; i < EPT; ++i) {
                const float d = fmaxf(z[i] - t, 0.f);
                s2 = fmaf(d, d, s2);
                s1 += d;
            }
            s1 = wave_sum(s1);
            s2 = wave_sum(s2);
            __syncthreads();
            if (lane == 0) { redA[wave] = s1; redB[wave] = s2; }
            __syncthreads();
            s1 = (redA[0] + redA[1]) + (redA[2] + redA[3]);
            s2 = (redB[0] + redB[1]) + (redB[2] + redB[3]);
            const float step = (s2 - 1.0f) / (2.0f * s1);
            t += step;                                  // block-uniform
            if (__builtin_fabsf(step) < 5e-7f) break;   // block-uniform
        }
    }

    // Epilogue: p = relu(z - tau)^2, coalesced nontemporal float4 stores
    // (out is write-once/never-read: don't evict unread input rows from L3).
    #pragma unroll
    for (int c = 0; c < NLD; ++c) {
        const int base = c * 1024 + tid * 4;
        f32x4 o;
        float d;
        d = fmaxf(z[c * 4 + 0] - t, 0.f); o.x = d * d;
        d = fmaxf(z[c * 4 + 1] - t, 0.f); o.y = d * d;
        d = fmaxf(z[c * 4 + 2] - t, 0.f); o.z = d * d;
        d = fmaxf(z[c * 4 + 3] - t, 0.f); o.w = d * d;
        __builtin_nontemporal_store(o, reinterpret_cast<f32x4*>(orow + base));
    }
}

extern "C" void kernel_launch(void* const* d_in, const int* in_sizes, int n_in,
                              void* d_out, int out_size, void* d_ws, size_t ws_size,
                              hipStream_t stream)
{
    const float* scores = (const float*)d_in[0];
    const int*   mask   = (const int*)d_in[1];
    float*       out    = (float*)d_out;

    dim3 grid(NROWS);    // one 256-thread block per row
    dim3 block(256);
    hipLaunchKernelGGL(entmax15_kernel, grid, block, 0, stream,
                       scores, mask, out);
}